// Round 4
// baseline (473.747 us; speedup 1.0000x reference)
//
#include <hip/hip_runtime.h>

#define C_   128
#define P_   4096
#define K3   384
#define CP   (C_*P_)
#define NB_  32

typedef __attribute__((ext_vector_type(8))) short short8;
typedef __attribute__((ext_vector_type(4))) short short4v;
typedef __attribute__((ext_vector_type(4))) float f32x4;

__device__ __forceinline__ short f2bf(float f) {
  union { float f; unsigned u; } v; v.f = f;
  unsigned r = v.u + 0x7fffu + ((v.u >> 16) & 1u);
  return (short)(r >> 16);
}
__device__ __forceinline__ float bf2f(short b) {
  union { unsigned u; float f; } v; v.u = ((unsigned)(unsigned short)b) << 16;
  return v.f;
}
__device__ __forceinline__ void gl_lds16(const void* g, void* l) {
  __builtin_amdgcn_global_load_lds(
      (const __attribute__((address_space(1))) unsigned int*)g,
      (__attribute__((address_space(3))) unsigned int*)l, 16, 0, 0);
}

__device__ __forceinline__ void mfma_phase(const short (*As_)[128][8],
                                           const short (*Bs_)[128][8],
                                           f32x4 acc[4][4], int lane, int wm, int wp) {
  int row = lane & 15, q = lane >> 4;
  short8 a[4], bb[4];
#pragma unroll
  for (int im = 0; im < 4; ++im) a[im] = *(const short8*)(&As_[q][wm + im * 16 + row][0]);
#pragma unroll
  for (int ip = 0; ip < 4; ++ip) bb[ip] = *(const short8*)(&Bs_[q][wp + ip * 16 + row][0]);
#pragma unroll
  for (int im = 0; im < 4; ++im)
#pragma unroll
    for (int ip = 0; ip < 4; ++ip)
      acc[im][ip] = __builtin_amdgcn_mfma_f32_16x16x32_bf16(a[im], bb[ip], acc[im][ip], 0, 0, 0);
}

// ---- xk: x -> xb (bf16 [c][p]) + xT (bf16 [p][c]); tail blocks: weight permute + zbuf ----
__global__ __launch_bounds__(256) void xk_kernel(const float* __restrict__ x,
                                                 const float* __restrict__ w3,
                                                 const float* __restrict__ w6,
                                                 short* __restrict__ xb,
                                                 short* __restrict__ xT,
                                                 short* __restrict__ w3p,
                                                 short* __restrict__ w6p,
                                                 short* __restrict__ zbuf) {
  int b = blockIdx.x;
  if (b >= 4096) {                       // 192 weight blocks
    int idx = (b - 4096) * 256 + threadIdx.x;   // [0, 49152)
    int m = idx / K3, kp = idx - m * K3;
    int j = kp >> 7, c = kp & 127;
    w3p[idx] = f2bf(w3[m * K3 + c * 3 + j]);
    w6p[idx] = f2bf(w6[m * K3 + c * 3 + j]);
    if (idx < 16) zbuf[idx] = 0;
    return;
  }
  int pt = b & 63, ct = (b >> 6) & 1, n = b >> 7;
  int p0 = pt * 64, c0 = ct * 64;
  const float* xn = x + (size_t)n * CP;
  short* xbn = xb + (size_t)n * CP;
  short* xTn = xT + (size_t)n * CP;
  __shared__ short Ls[64][68];
  int tid = threadIdx.x;
#pragma unroll
  for (int it = 0; it < 4; ++it) {
    int fid = tid + it * 256;
    int i = fid >> 4, j4 = fid & 15;
    f32x4 v = *(const f32x4*)(xn + (c0 + i) * P_ + p0 + j4 * 4);
    short4v s;
#pragma unroll
    for (int r = 0; r < 4; ++r) s[r] = f2bf(v[r]);
    *(short4v*)(xbn + (c0 + i) * P_ + p0 + j4 * 4) = s;
    *(short4v*)(&Ls[i][j4 * 4]) = s;
  }
  __syncthreads();
#pragma unroll
  for (int it = 0; it < 4; ++it) {
    int oid = tid + it * 256;
    int pr = oid >> 4, cg = oid & 15, cb = cg * 4;
    short4v a;
#pragma unroll
    for (int r = 0; r < 4; ++r) a[r] = Ls[cb + r][pr];
    *(short4v*)(xTn + (p0 + pr) * C_ + c0 + cb) = a;
  }
}

// ---- g12: role1: t3T = w3 @ t1 ; role0: t6T/t7T from w6 @ t5(on-the-fly); pipelined dbuf ----
__global__ __launch_bounds__(256) void g12_kernel(const short* __restrict__ w3p,
                                                  const short* __restrict__ w6p,
                                                  const float* __restrict__ p5,
                                                  const short* __restrict__ xT,
                                                  const short* __restrict__ zbuf,
                                                  short* __restrict__ t3T,
                                                  short* __restrict__ t6T,
                                                  short* __restrict__ t7T) {
  int blk = blockIdx.x;
  int role = blk & 1;
  int b = blk >> 1;
  int n = b >> 5, pt = b & 31, p0 = pt * 128;
  int tid = threadIdx.x, lane = tid & 63, wv = tid >> 6;
  int wm = (wv & 1) * 64, wp = (wv >> 1) * 64;
  const short* Ap = role ? w3p : w6p;
  const short* xTn = xT + (size_t)n * CP;
  __shared__ __align__(16) short As[2][4][128][8];
  __shared__ __align__(16) short Bs[2][4][128][8];
  f32x4 acc[4][4] = {};
  int q_[2], pc_[2];
#pragma unroll
  for (int it = 0; it < 2; ++it) { int s = tid + it * 256; q_[it] = s >> 7; pc_[it] = s & 127; }

  short8 rl[2], rm[2], rr[2];
  float rp5[2];

  auto dmaA = [&](int ks, int buf) {
#pragma unroll
    for (int it = 0; it < 2; ++it)
      gl_lds16(Ap + pc_[it] * K3 + ks * 32 + q_[it] * 8, &As[buf][q_[it]][pc_[it]][0]);
  };
  auto dmaB1 = [&](int ks, int buf) {          // role1: straight DMA, zeros for invalid
    int jr = ks >> 2, d = 2 * (jr - 1);
#pragma unroll
    for (int it = 0; it < 2; ++it) {
      int p = p0 + pc_[it];
      int c0k = ((ks & 3) * 32) + q_[it] * 8;
      int wd = (p & 63) + d;
      bool valid = (wd >= 0 && wd < 64);
      const short* src = valid ? (xTn + (size_t)(p + d) * C_ + c0k) : zbuf;
      gl_lds16(src, &Bs[buf][q_[it]][pc_[it]][0]);
    }
  };
  auto preloadB0 = [&](int ks) {               // role0: t5 inputs into regs
    int jr = ks >> 2;
#pragma unroll
    for (int it = 0; it < 2; ++it) {
      int p = p0 + pc_[it];
      int c0k = ((ks & 3) * 32) + q_[it] * 8;
      int pr = p + 192 * (jr - 1);
      bool rv = (pr >= 0 && pr < P_);
      int prc = min(max(pr, 0), P_ - 1);
      int w2 = prc & 63;
      const short* rb = xTn + (size_t)prc * C_ + c0k;
      short8 zero = {};
      rm[it] = rv ? *(const short8*)rb : zero;
      rl[it] = (rv && w2 >= 2) ? *(const short8*)(rb - 2 * C_) : zero;
      rr[it] = (rv && w2 < 62) ? *(const short8*)(rb + 2 * C_) : zero;
      rp5[it] = rv ? p5[prc] : 0.f;
    }
  };
  auto writeB0 = [&](int buf) {
#pragma unroll
    for (int it = 0; it < 2; ++it) {
      short8 v;
#pragma unroll
      for (int jj = 0; jj < 8; ++jj)
        v[jj] = f2bf(rp5[it] * fmaxf(fmaxf(bf2f(rl[it][jj]), bf2f(rm[it][jj])), bf2f(rr[it][jj])));
      *(short8*)(&Bs[buf][q_[it]][pc_[it]][0]) = v;
    }
  };

  dmaA(0, 0);
  if (role) dmaB1(0, 0); else preloadB0(0);

  for (int ks = 0; ks < 12; ++ks) {
    int buf = ks & 1, nbuf = buf ^ 1;
    if (!role) writeB0(buf);
    __syncthreads();
    int ksn = (ks + 1 < 12) ? ks + 1 : ks;
    dmaA(ksn, nbuf);
    if (role) dmaB1(ksn, nbuf); else preloadB0(ksn);
    mfma_phase(As[buf], Bs[buf], acc, lane, wm, wp);
  }

  int col = lane & 15, rq = lane >> 4;
  if (role) {
    short* t3Tn = t3T + (size_t)n * CP;
#pragma unroll
    for (int im = 0; im < 4; ++im)
#pragma unroll
      for (int ip = 0; ip < 4; ++ip) {
        int m0 = wm + im * 16 + rq * 4;
        int p = p0 + wp + ip * 16 + col;
        short4v s;
#pragma unroll
        for (int r = 0; r < 4; ++r) s[r] = f2bf(acc[im][ip][r]);
        *(short4v*)(t3Tn + (size_t)p * C_ + m0) = s;
      }
  } else {
    short* t6Tn = t6T + (size_t)n * CP;
    short* t7Tn = t7T + (size_t)n * CP;
#pragma unroll
    for (int im = 0; im < 4; ++im)
#pragma unroll
      for (int ip = 0; ip < 4; ++ip) {
        int m0 = wm + im * 16 + rq * 4;
        int p = p0 + wp + ip * 16 + col;
        short4v ax = *(const short4v*)(xTn + (size_t)p * C_ + m0);
        short4v s6, s7;
#pragma unroll
        for (int r = 0; r < 4; ++r) {
          float t6v = acc[im][ip][r];
          float t7v = fmaxf(bf2f(ax[r]), t6v);
          s6[r] = f2bf(t6v);
          s7[r] = f2bf(t7v);
        }
        *(short4v*)(t6Tn + (size_t)p * C_ + m0) = s6;
        *(short4v*)(t7Tn + (size_t)p * C_ + m0) = s7;
      }
  }
}

// ---- g3: t9T[k'][c] += sum_p t1[k',p] * t7T[p][c]  (split-K=8, pipelined dbuf) ----
__global__ __launch_bounds__(256) void g3_kernel(const short* __restrict__ xb,
                                                 const short* __restrict__ t7T,
                                                 float* __restrict__ t9) {
  int blk = blockIdx.x;                 // 768 = 3 * 32 * 8
  int nb = blk % 3;
  int tmp = blk / 3;
  int n = tmp & 31, sk = tmp >> 5;
  int d = 2 * (nb - 1);
  int tid = threadIdx.x, lane = tid & 63, wv = tid >> 6;
  int wm = (wv & 1) * 64, wp = (wv >> 1) * 64;
  const short* xbn = xb + (size_t)n * CP;
  const short* t7n = t7T + (size_t)n * CP;
  __shared__ __align__(16) short As[2][4][128][8];
  __shared__ __align__(16) short Bs[2][4][128][8];
  f32x4 acc[4][4] = {};
  int q_[2], kc_[2];
#pragma unroll
  for (int it = 0; it < 2; ++it) { int s = tid + it * 256; q_[it] = s >> 7; kc_[it] = s & 127; }

  int ra[2][4];
  short8 rbv[2];

  auto dmaA1 = [&](int ks, int buf) {          // nb==1: aligned straight copy
#pragma unroll
    for (int it = 0; it < 2; ++it)
      gl_lds16(xbn + kc_[it] * P_ + sk * 512 + ks * 32 + q_[it] * 8,
               &As[buf][q_[it]][kc_[it]][0]);
  };
  auto preloadA = [&](int ks) {
#pragma unroll
    for (int it = 0; it < 2; ++it) {
      int pb = sk * 512 + ks * 32 + q_[it] * 8;
      const int* src = (const int*)(xbn + kc_[it] * P_ + pb + d);
#pragma unroll
      for (int t = 0; t < 4; ++t) ra[it][t] = src[t];
    }
  };
  auto writeA = [&](int ks, int buf) {
#pragma unroll
    for (int it = 0; it < 2; ++it) {
      union { int i[4]; short8 s; } u;
#pragma unroll
      for (int t = 0; t < 4; ++t) u.i[t] = ra[it][t];
      short8 v = u.s;
      int w0 = (sk * 512 + ks * 32 + q_[it] * 8) & 63;
      if (nb == 0) { if (w0 == 0) { v[0] = 0; v[1] = 0; } }
      else if (nb == 2) { if (w0 == 56) { v[6] = 0; v[7] = 0; } }
      *(short8*)(&As[buf][q_[it]][kc_[it]][0]) = v;
    }
  };
  auto preloadB = [&](int ks) {
#pragma unroll
    for (int it = 0; it < 2; ++it) {
      const short* bp = t7n + (size_t)(sk * 512 + ks * 32 + q_[it] * 8) * C_ + kc_[it];
      short8 v;
#pragma unroll
      for (int j = 0; j < 8; ++j) v[j] = bp[j * C_];
      rbv[it] = v;
    }
  };
  auto writeB = [&](int buf) {
#pragma unroll
    for (int it = 0; it < 2; ++it)
      *(short8*)(&Bs[buf][q_[it]][kc_[it]][0]) = rbv[it];
  };

  if (nb == 1) dmaA1(0, 0); else preloadA(0);
  preloadB(0);

  for (int ks = 0; ks < 16; ++ks) {
    int buf = ks & 1, nbuf = buf ^ 1;
    if (nb != 1) writeA(ks, buf);
    writeB(buf);
    __syncthreads();
    int ksn = (ks + 1 < 16) ? ks + 1 : ks;
    if (nb == 1) dmaA1(ksn, nbuf); else preloadA(ksn);
    preloadB(ksn);
    mfma_phase(As[buf], Bs[buf], acc, lane, wm, wp);
  }

  int col = lane & 15, rq = lane >> 4;
  float* t9n = t9 + (size_t)n * (K3 * C_);
#pragma unroll
  for (int im = 0; im < 4; ++im)
#pragma unroll
    for (int ip = 0; ip < 4; ++ip)
#pragma unroll
      for (int r = 0; r < 4; ++r) {
        int kp = nb * 128 + wm + im * 16 + rq * 4 + r;
        int c = wp + ip * 16 + col;
        atomicAdd(&t9n[(size_t)kp * C_ + c], acc[im][ip][r]);
      }
}

// ---- g4: out[c][p] = sum_k' (p8[c]*scale*t9T[k'][c]) * t12[k'][p]  (pipelined dbuf) ----
__global__ __launch_bounds__(256) void g4_kernel(const float* __restrict__ t9,
                                                 const float* __restrict__ p8,
                                                 const float* __restrict__ p12,
                                                 const short* __restrict__ t3T,
                                                 const short* __restrict__ t6T,
                                                 const short* __restrict__ t7T,
                                                 const short* __restrict__ xT,
                                                 float* __restrict__ out) {
  int b = blockIdx.x;                    // 1024
  int n = b >> 5, pt = b & 31, p0 = pt * 128;
  int tid = threadIdx.x, lane = tid & 63, wv = tid >> 6;
  int wm = (wv & 1) * 64, wp = (wv >> 1) * 64;
  const float* t9n = t9 + (size_t)n * (K3 * C_);
  const short* t3n = t3T + (size_t)n * CP;
  const short* t6n = t6T + (size_t)n * CP;
  const short* t7n = t7T + (size_t)n * CP;
  const short* xTn = xT + (size_t)n * CP;
  const float INV = 1.0f / (64.0f * 19.5959179423f);    // 1/(64*sqrt(384))
  __shared__ __align__(16) short As[2][4][128][8];
  __shared__ __align__(16) short Bs[2][4][128][8];
  f32x4 acc[4][4] = {};
  int q_[2], m_[2];
#pragma unroll
  for (int it = 0; it < 2; ++it) { int s = tid + it * 256; q_[it] = s >> 7; m_[it] = s & 127; }
  float psc[2];
#pragma unroll
  for (int it = 0; it < 2; ++it) psc[it] = p8[m_[it]] * INV;

  float raf[2][8];
  short8 rb6[2], rb7[2], rb3[2], rbx[2];
  float rs12[2];

  auto preloadA = [&](int ks) {
#pragma unroll
    for (int it = 0; it < 2; ++it)
#pragma unroll
      for (int jj = 0; jj < 8; ++jj)
        raf[it][jj] = t9n[(size_t)(ks * 32 + q_[it] * 8 + jj) * C_ + m_[it]];
  };
  auto writeA = [&](int buf) {
#pragma unroll
    for (int it = 0; it < 2; ++it) {
      short8 v;
#pragma unroll
      for (int jj = 0; jj < 8; ++jj) v[jj] = f2bf(raf[it][jj] * psc[it]);
      *(short8*)(&As[buf][q_[it]][m_[it]][0]) = v;
    }
  };
  auto preloadB = [&](int ks) {
    int j = ks >> 2, d = 2 * (j - 1);
#pragma unroll
    for (int it = 0; it < 2; ++it) {
      int p = p0 + m_[it];
      int c0k = ((ks & 3) * 32) + q_[it] * 8;
      size_t base = (size_t)p * C_ + c0k;
      rb6[it] = *(const short8*)(t6n + base);
      rb7[it] = *(const short8*)(t7n + base);
      rb3[it] = *(const short8*)(t3n + base);
      int wd = (p & 63) + d;
      bool valid = (wd >= 0 && wd < 64);
      int pr = min(max(p + d, 0), P_ - 1);
      short8 ax = *(const short8*)(xTn + (size_t)pr * C_ + c0k);
      short8 zero = {};
      rbx[it] = valid ? ax : zero;
      rs12[it] = p12[j * 64 + (p >> 6)];
    }
  };
  auto writeB = [&](int buf) {
#pragma unroll
    for (int it = 0; it < 2; ++it) {
      short8 v;
#pragma unroll
      for (int jj = 0; jj < 8; ++jj) {
        float t11 = fmaxf(bf2f(rb6[it][jj]),
                          bf2f(rb7[it][jj]) + fmaxf(bf2f(rb3[it][jj]), bf2f(rbx[it][jj])));
        v[jj] = f2bf(rs12[it] * t11);
      }
      *(short8*)(&Bs[buf][q_[it]][m_[it]][0]) = v;
    }
  };

  preloadA(0);
  preloadB(0);

  for (int ks = 0; ks < 12; ++ks) {
    int buf = ks & 1, nbuf = buf ^ 1;
    writeA(buf);
    writeB(buf);
    __syncthreads();
    int ksn = (ks + 1 < 12) ? ks + 1 : ks;
    preloadA(ksn);
    preloadB(ksn);
    mfma_phase(As[buf], Bs[buf], acc, lane, wm, wp);
  }

  int col = lane & 15, rq = lane >> 4;
#pragma unroll
  for (int im = 0; im < 4; ++im)
#pragma unroll
    for (int ip = 0; ip < 4; ++ip)
#pragma unroll
      for (int r = 0; r < 4; ++r) {
        int m = wm + im * 16 + rq * 4 + r;
        int p = p0 + wp + ip * 16 + col;
        out[(size_t)n * CP + m * P_ + p] = acc[im][ip][r];
      }
}

extern "C" void kernel_launch(void* const* d_in, const int* in_sizes, int n_in,
                              void* d_out, int out_size, void* d_ws, size_t ws_size,
                              hipStream_t stream) {
  const float* x   = (const float*)d_in[0];
  const float* w3  = (const float*)d_in[1];
  const float* p5  = (const float*)d_in[2];
  const float* w6  = (const float*)d_in[3];
  const float* p8  = (const float*)d_in[4];
  const float* p12 = (const float*)d_in[5];
  float* out = (float*)d_out;

  char* ws = (char*)d_ws;
  const size_t RB = (size_t)NB_ * CP * 2;        // 32 MiB per bf16 tensor
  size_t off = 256;                              // guard for small negative-shift reads
  short* xb  = (short*)(ws + off); off += RB;
  short* xT  = (short*)(ws + off); off += RB;
  short* t3T = (short*)(ws + off); off += RB;
  short* t6T = (short*)(ws + off); off += RB;
  short* t7T = (short*)(ws + off); off += RB;
  float* t9  = (float*)(ws + off); off += (size_t)NB_ * K3 * C_ * 4;   // t9T [n][384][128]
  short* w3p = (short*)(ws + off); off += 49152 * 2;
  short* w6p = (short*)(ws + off); off += 49152 * 2;
  short* zbuf = (short*)(ws + off); off += 64;   // 16 zero shorts, 16B-aligned

  xk_kernel<<<4288, 256, 0, stream>>>(x, w3, w6, xb, xT, w3p, w6p, zbuf);
  hipMemsetAsync(t9, 0, (size_t)NB_ * K3 * C_ * sizeof(float), stream);
  g12_kernel<<<2048, 256, 0, stream>>>(w3p, w6p, p5, xT, zbuf, t3T, t6T, t7T);
  g3_kernel<<<768, 256, 0, stream>>>(xb, t7T, t9);
  g4_kernel<<<1024, 256, 0, stream>>>(t9, p8, p12, t3T, t6T, t7T, xT, out);
}